// Round 12
// baseline (13900.343 us; speedup 1.0000x reference)
//
#include <hip/hip_runtime.h>
#include <hip/hip_bf16.h>

// ============================================================================
// GRU seq2seq (3-layer enc + 3-cell dec + linear), B=2048, H=60, F=1, fp32.
//
// Round 12 = round 9 kernel (best, 681us/phase) with TWO independent barrier
// domains per CU:
//  - 512 blocks x 4 valid rows (12 M-pad rows), __launch_bounds__(768, 6):
//    2 blocks/CU, each with its own s_barrier -> phases drift -> one block's
//    activation (trans-heavy) overlaps the other's MFMA/LDS. r9 measures
//    VGPR=84, budget at 6 waves/EU is 85 -> fits without spill.
//  - Global I/O (x prefetch, hfin, y) guarded to valid rows (q16==0).
//  - Per-wave code otherwise IDENTICAL to r9: f16 single-plane ring (stride
//    72), mmh h-path (W hi+lo) / mmx x-path (hi), fp32 h in regs, y via MFMA
//    on g0w0, lgkmcnt-only barrier.
// ============================================================================

typedef float    f32x4 __attribute__((ext_vector_type(4)));
typedef _Float16 f16x8 __attribute__((ext_vector_type(8)));

#define RSTR 72               // ring row stride in shorts
#define REG  (16 * RSTR)      // shorts per region
#define ROWS 4
#define NBLK (2048 / ROWS)

struct CellB  { const float* bih; const float* bhh; const float* wih_vec; };
struct PhaseArgs {
  const float* xseq;          // [2048][512] fp32
  const unsigned short* frags;
  CellB cell[3];
  const float* hfin_rd;       // dec: [3][2048][64] fp32
  float* hfin_wr;             // enc
  const float* lin_b;         // [1]
  float* y;                   // [2048][512]
};
struct PrepArgs {
  const float* w[13];         // (wih,whh) x 6 cells, then lin_w
  int din[13];
  unsigned short* out;
};

union HU { _Float16 h; unsigned short u; };
__device__ __forceinline__ unsigned short f2h(float x) { HU c; c.h = (_Float16)x; return c.u; }
__device__ __forceinline__ float h2f(unsigned short s) { HU c; c.u = s; return (float)c.h; }
__device__ __forceinline__ void wg_barrier() {
  asm volatile("s_waitcnt lgkmcnt(0)" ::: "memory");
  __builtin_amdgcn_s_barrier();
}

// ---------------------------------------------------------------------------
// Prep: f16 B-fragments (hi = f16(v), lo = f16(v - float(hi))) for 6 cells x
// {wih,whh} (cm 0..11) and lin_w (cm 12, tile 0, col 0).
// frag_idx = (cm*12+tile)*4 + s2*2 + sp; short off = frag_idx*512 + lane*8 + e.
// element: col c = tile*16+(lane&15); k = s2*32+(lane>>4)*8+e.
// ---------------------------------------------------------------------------
__global__ void prep_frags(PrepArgs P) {
  int id = blockIdx.x * 256 + threadIdx.x;       // 1248*256 = 319488
  int e    = id & 7;
  int lane = (id >> 3) & 63;
  int sp   = (id >> 9) & 1;
  int s2   = (id >> 10) & 1;
  int rest = id >> 11;
  int tile = rest % 12;
  int cm   = rest / 12;
  if (cm > 12) return;
  const float* W = P.w[cm];
  int din = P.din[cm];
  int c = tile * 16 + (lane & 15);
  int k = s2 * 32 + (lane >> 4) * 8 + e;
  float v = 0.f;
  if (cm == 12) {
    if (c == 0 && k < 60) v = W[k];              // lin_w row
  } else {
    int j = c & 63, sec = c >> 6;
    if (j < 60 && k < din) v = W[(sec * 60 + j) * din + k];
  }
  unsigned short hi = f2h(v);
  unsigned short o = sp ? f2h(v - h2f(hi)) : hi;
  P.out[id] = o;
}

// h-path: A x (Whi + Wlo), two independent 2-deep chains (4 MFMA)
__device__ __forceinline__ f32x4 mmh(f32x4 acc, const f16x8 A0, const f16x8 A1,
                                     const f16x8 B[2][2]) {
  f32x4 a2 = {0.f, 0.f, 0.f, 0.f};
  acc = __builtin_amdgcn_mfma_f32_16x16x32_f16(A0, B[0][0], acc, 0, 0, 0);
  a2  = __builtin_amdgcn_mfma_f32_16x16x32_f16(A0, B[0][1], a2,  0, 0, 0);
  acc = __builtin_amdgcn_mfma_f32_16x16x32_f16(A1, B[1][0], acc, 0, 0, 0);
  a2  = __builtin_amdgcn_mfma_f32_16x16x32_f16(A1, B[1][1], a2,  0, 0, 0);
  return acc + a2;
}
// x-path: A x Whi only (2 MFMA, one chain)
__device__ __forceinline__ f32x4 mmx(f32x4 acc, const f16x8 A0, const f16x8 A1,
                                     const f16x8 B[2]) {
  acc = __builtin_amdgcn_mfma_f32_16x16x32_f16(A0, B[0], acc, 0, 0, 0);
  acc = __builtin_amdgcn_mfma_f32_16x16x32_f16(A1, B[1], acc, 0, 0, 0);
  return acc;
}

// ---------------------------------------------------------------------------
// Fused 3-stage GRU pipeline. IS_DEC=0: encoder; IS_DEC=1: decoder (+linear).
// Ring: [region 0..5][row 0..15][col 0..63 of RSTR] f16; region = g*2+parity.
// ---------------------------------------------------------------------------
template <int IS_DEC>
__global__ __launch_bounds__(768, 6) void gru_phase(PhaseArgs P) {
  __shared__ alignas(16) unsigned short ring[6 * REG];

  const int tid  = threadIdx.x;
  const int lane = tid & 63;
  const int wid  = tid >> 6;
  const int g    = wid >> 2;      // layer/cell 0..2
  const int w    = wid & 3;       // col-tile 0..3
  const int c16  = lane & 15;
  const int q16  = lane >> 4;
  const int row_base = blockIdx.x * ROWS;
  const int c    = w * 16 + c16;  // logical h-col 0..63
  const bool cv  = (c < 60);
  const int cell = (IS_DEC ? 3 : 0) + g;
  const bool din1 = (g == 0);
  const bool yduty = (IS_DEC && g == 0 && w == 0);
  const bool rv   = (q16 == 0);   // rows 4*q16+q valid only for q16==0

  // per-lane LDS offsets (shorts)
  int wo[4];
#pragma unroll
  for (int q = 0; q < 4; ++q) wo[q] = (4 * q16 + q) * RSTR + c;
  const int ro0 = c16 * RSTR + q16 * 8;
  const int ro1 = ro0 + 32;

  // per-lane constants
  const float* bih = P.cell[g].bih;
  const float* bhh = P.cell[g].bhh;
  float b_r  = cv ? bih[c] + bhh[c]           : 0.f;
  float b_z  = cv ? bih[60 + c] + bhh[60 + c] : 0.f;
  float b_hn = cv ? bhh[120 + c]              : 0.f;
  float b_in = cv ? bih[120 + c]              : 0.f;
  float w_r = 0.f, w_z = 0.f, w_n = 0.f;
  if (din1 && cv) {
    const float* wv = P.cell[g].wih_vec;
    w_r = wv[c]; w_z = wv[60 + c]; w_n = wv[120 + c];
  }

  // persistent weight fragments: Bh hi/lo, Bx hi only
  f16x8 Bh[3][2][2], Bx[3][2];
#pragma unroll
  for (int T = 0; T < 3; ++T)
#pragma unroll
    for (int s2 = 0; s2 < 2; ++s2) {
      const int tile = w + 4 * T;
#pragma unroll
      for (int sp = 0; sp < 2; ++sp)
        Bh[T][s2][sp] = *(const f16x8*)(P.frags +
            (size_t)(((cell * 2 + 1) * 12 + tile) * 4 + s2 * 2 + sp) * 512 + lane * 8);
      Bx[T][s2] = *(const f16x8*)(P.frags +
          (size_t)(((cell * 2 + 0) * 12 + tile) * 4 + s2 * 2 + 0) * 512 + lane * 8);
    }
  f16x8 Lw[2];
  float lb = 0.f;
  if (IS_DEC) {
    lb = P.lin_b[0];
#pragma unroll
    for (int s2 = 0; s2 < 2; ++s2)
      Lw[s2] = *(const f16x8*)(P.frags +
          (size_t)((12 * 12 + 0) * 4 + s2 * 2 + 0) * 512 + lane * 8);
  }

  // h0 (enc: zeros; dec: encoder final h, valid rows only) into parity-1 region
  float hreg[4];
#pragma unroll
  for (int q = 0; q < 4; ++q) {
    float h0 = 0.f;
    if (IS_DEC && cv && rv)
      h0 = P.hfin_rd[((size_t)(2 - g) * 2048 + row_base + q) * 64 + c];
    hreg[q] = h0;
    ring[(g * 2 + 1) * REG + wo[q]] = f2h(h0);
  }

  // x prefetch (t=0) for g0 (valid rows only)
  float xcur[4] = {0.f, 0.f, 0.f, 0.f};
  if (din1 && rv) {
    const float* xp = P.xseq + (size_t)row_base * 512;
#pragma unroll
    for (int q = 0; q < 4; ++q) xcur[q] = xp[(size_t)q * 512];
  }
  wg_barrier();

#pragma unroll 1
  for (int s = 0; s < 514; ++s) {
    // decoder y_{s-3} = h2_{s-3} @ lin_w + lin_b (MFMA on g0w0)
    if (yduty && s >= 3) {
      const int yb = (4 + ((s + 1) & 1)) * REG;
      f16x8 Y0 = *(const f16x8*)(ring + yb + ro0);
      f16x8 Y1 = *(const f16x8*)(ring + yb + ro1);
      f32x4 ya = {lb, lb, lb, lb};
      ya = mmx(ya, Y0, Y1, Lw);
      if (c16 == 0 && q16 == 0) {
#pragma unroll
        for (int q = 0; q < 4; ++q)
          P.y[(size_t)(row_base + q) * 512 + (s - 3)] = ya[q];
      }
    }

    const int t = s - g;
    if (t >= 0 && t < 512) {
      // ---- A loads up front (single f16 plane)
      const int oR = (g * 2 + ((t + 1) & 1)) * REG;
      f16x8 A0 = *(const f16x8*)(ring + oR + ro0);
      f16x8 A1 = *(const f16x8*)(ring + oR + ro1);
      f16x8 X0, X1;
      if (!din1) {
        const int oX = ((g - 1) * 2 + (t & 1)) * REG;
        X0 = *(const f16x8*)(ring + oX + ro0);
        X1 = *(const f16x8*)(ring + oX + ro1);
      }

      f32x4 aR  = {b_r, b_r, b_r, b_r};
      f32x4 aZ  = {b_z, b_z, b_z, b_z};
      f32x4 aHN = {b_hn, b_hn, b_hn, b_hn};
      f32x4 aIN = {b_in, b_in, b_in, b_in};
      aR  = mmh(aR,  A0, A1, Bh[0]);
      aZ  = mmh(aZ,  A0, A1, Bh[1]);
      aHN = mmh(aHN, A0, A1, Bh[2]);

      if (din1) {
#pragma unroll
        for (int q = 0; q < 4; ++q) {
          aR[q]  += xcur[q] * w_r;
          aZ[q]  += xcur[q] * w_z;
          aIN[q] += xcur[q] * w_n;
        }
        if (rv && t + 1 < 512) {                // prefetch next step's x
          const float* xp = P.xseq + (size_t)row_base * 512 + (t + 1);
#pragma unroll
          for (int q = 0; q < 4; ++q) xcur[q] = xp[(size_t)q * 512];
        }
      } else {
        aR  = mmx(aR,  X0, X1, Bx[0]);
        aZ  = mmx(aZ,  X0, X1, Bx[1]);
        aIN = mmx(aIN, X0, X1, Bx[2]);
      }

      // ---- activations + state update (full fp32), publish to parity t&1
      unsigned short* wp = ring + (g * 2 + (t & 1)) * REG;
#pragma unroll
      for (int q = 0; q < 4; ++q) {
        float r = __builtin_amdgcn_rcpf(1.f + __expf(-aR[q]));
        float z = __builtin_amdgcn_rcpf(1.f + __expf(-aZ[q]));
        float na = aIN[q] + r * aHN[q];
        float e2 = __expf(2.f * na);
        float n  = __builtin_fmaf(-2.f, __builtin_amdgcn_rcpf(e2 + 1.f), 1.f);
        float h  = n + z * (hreg[q] - n);
        hreg[q]  = h;
        wp[wo[q]] = f2h(h);
      }

      // ---- encoder: store final hidden state (valid rows only)
      if (!IS_DEC && t == 511 && rv) {
#pragma unroll
        for (int q = 0; q < 4; ++q)
          P.hfin_wr[((size_t)g * 2048 + row_base + q) * 64 + c] = hreg[q];
      }
    }
    wg_barrier();
  }

  // decoder epilogue: y_511 (h2_511 written at s=513 into region 5)
  if (yduty) {
    const int yb = 5 * REG;
    f16x8 Y0 = *(const f16x8*)(ring + yb + ro0);
    f16x8 Y1 = *(const f16x8*)(ring + yb + ro1);
    f32x4 ya = {lb, lb, lb, lb};
    ya = mmx(ya, Y0, Y1, Lw);
    if (c16 == 0 && q16 == 0) {
#pragma unroll
      for (int q = 0; q < 4; ++q)
        P.y[(size_t)(row_base + q) * 512 + 511] = ya[q];
    }
  }
}

// ---------------------------------------------------------------------------
extern "C" void kernel_launch(void* const* d_in, const int* in_sizes, int n_in,
                              void* d_out, int out_size, void* d_ws, size_t ws_size,
                              hipStream_t stream) {
  (void)in_sizes; (void)n_in; (void)out_size; (void)ws_size;
  const float* inputs  = (const float*)d_in[0];
  const float* outputs = (const float*)d_in[1];

  unsigned short* frags = (unsigned short*)d_ws;            // 638976 B
  float* hfin = (float*)((char*)d_ws + 655360);             // 1.5 MB

  static const int ofs[6]  = {2, 6, 10, 14, 18, 22};  // enc0,enc1,enc2,c1,c2,c3
  static const int dins[6] = {1, 60, 60, 1, 60, 60};

  PrepArgs pa;
  for (int ci = 0; ci < 6; ++ci) {
    pa.w[ci * 2 + 0]   = (const float*)d_in[ofs[ci] + 0];  // wih
    pa.w[ci * 2 + 1]   = (const float*)d_in[ofs[ci] + 1];  // whh
    pa.din[ci * 2 + 0] = dins[ci];
    pa.din[ci * 2 + 1] = 60;
  }
  pa.w[12]   = (const float*)d_in[26];                     // lin_w
  pa.din[12] = 60;
  pa.out = frags;
  prep_frags<<<dim3(1248), dim3(256), 0, stream>>>(pa);

  PhaseArgs ea;
  ea.xseq = inputs; ea.frags = frags;
  for (int gg = 0; gg < 3; ++gg) {
    ea.cell[gg].bih     = (const float*)d_in[ofs[gg] + 2];
    ea.cell[gg].bhh     = (const float*)d_in[ofs[gg] + 3];
    ea.cell[gg].wih_vec = (const float*)d_in[ofs[gg] + 0];
  }
  ea.hfin_rd = hfin; ea.hfin_wr = hfin;
  ea.lin_b = (const float*)d_in[27];
  ea.y = (float*)d_out;
  gru_phase<0><<<dim3(NBLK), dim3(768), 0, stream>>>(ea);

  PhaseArgs da = ea;
  da.xseq = outputs;
  for (int gg = 0; gg < 3; ++gg) {
    da.cell[gg].bih     = (const float*)d_in[ofs[3 + gg] + 2];
    da.cell[gg].bhh     = (const float*)d_in[ofs[3 + gg] + 3];
    da.cell[gg].wih_vec = (const float*)d_in[ofs[3 + gg] + 0];
  }
  gru_phase<1><<<dim3(NBLK), dim3(768), 0, stream>>>(da);
}